// Round 1
// baseline (794.823 us; speedup 1.0000x reference)
//
#include <hip/hip_runtime.h>

// LTFGW semi-relaxed FGW marginals — MI355X (gfx950)
// One block per node (272 threads = 16 templates x 17 local rows).
// Per-thread: one row lt[k, a, 0..9] in registers; softmax is thread-local.
// T staged in LDS; q computed cooperatively; C1 as 17-bit masks (complement
// trick for dense rows); constC2+Y2 fused over shared C2-row reads.
// Exact simplifications: terms constant over the softmax axis (c1p, ||F1||^2,
// log(p)-log(MT)) are dropped — softmax-invariant.

#define NN    6000
#define DEG   16
#define MM    17      // M = DEG+1
#define NTPL  16      // NT
#define MT    10
#define NF    128
#define NITER 10

__global__ __launch_bounds__(272) void srfgw_kernel(
    const float* __restrict__ x,        // (6000,128)
    const int*   __restrict__ dst,      // edge_index[1], 96000
    const float* __restrict__ C2g,      // templates (16,10,10)
    const float* __restrict__ F2g,      // templates_features (16,10,128)
    const float* __restrict__ alpha0,   // (1,)
    float*       __restrict__ out)      // (6000,160)
{
    const int n   = blockIdx.x;
    const int tid = threadIdx.x;
    const int k   = tid / MM;           // template index 0..15
    const int a   = tid - k * MM;       // local row 0..16

    __shared__ __align__(16) float s_x[MM][NF];          // 8704 B
    __shared__ __align__(16) float s_T[NTPL][MM][MT];    // 10880 B
    __shared__ __align__(16) float s_C2[NTPL][MT][MT];   // 6400 B
    __shared__ __align__(16) float s_q[NTPL][MT];        // 640 B
    __shared__ __align__(16) float s_f2sq[NTPL * MT];    // 640 B
    __shared__ int      s_nbr[MM];
    __shared__ unsigned s_mask[MM];

    // ---- neighbor list + zero masks ----
    if (tid < MM) {
        s_nbr[tid]  = (tid == 0) ? n : dst[n * DEG + tid - 1];
        s_mask[tid] = 0u;
    }
    // ---- stage C2 (no dependency on s_nbr) ----
    {
        float* sc2 = &s_C2[0][0][0];
        for (int i = tid; i < NTPL * MT * MT; i += 272) sc2[i] = C2g[i];
    }
    __syncthreads();

    // ---- stage x rows for the 17 neighbors (float4, coalesced) ----
    {
        const float4* xg  = reinterpret_cast<const float4*>(x);
        float4*       sx4 = reinterpret_cast<float4*>(&s_x[0][0]);
        for (int i = tid; i < MM * (NF / 4); i += 272) {
            int row = i >> 5;           // NF/4 = 32 float4 per row
            int col = i & 31;
            sx4[i] = xg[(long)s_nbr[row] * (NF / 4) + col];
        }
    }
    // ---- f2sq[kt] = ||F2[k,t]||^2 (cooperative, one-time) ----
    for (int kt = tid; kt < NTPL * MT; kt += 272) {
        const float4* f2 = reinterpret_cast<const float4*>(F2g + kt * NF);
        float s = 0.f;
        #pragma unroll 8
        for (int f = 0; f < NF / 4; f++) {
            float4 v = f2[f];
            s += v.x * v.x + v.y * v.y + v.z * v.z + v.w * v.w;
        }
        s_f2sq[kt] = s;
    }
    // ---- C1 bitmasks: A_sym[u][v] = (v in adj(u)) or (u in adj(v)) ----
    for (int p = tid; p < MM * MM; p += 272) {
        int pa = p / MM, pb = p - pa * MM;
        int u = s_nbr[pa], v = s_nbr[pb];
        const int* du = dst + (long)u * DEG;
        const int* dv = dst + (long)v * DEG;
        bool e = false;
        #pragma unroll
        for (int j = 0; j < DEG; j++) e = e | (du[j] == v) | (dv[j] == u);
        if (e) atomicOr(&s_mask[pa], 1u << pb);
    }
    __syncthreads();

    // ---- per-thread constants ----
    const float aval   = alpha0[0];
    const float alpha  = 1.f / (1.f + __expf(-aval));
    const float invreg = 1.0f / 0.1f;
    const float gcoef  = 2.f * alpha * invreg;          // on (constC2 - 2*Y2)
    const float mcoef  = (1.f - alpha) * invreg;        // on Mcost (t-varying part)

    // ---- Mc[t] = mcoef * ( ||F2[k,t]||^2 - 2 <x[nbr_a], F2[k,t]> ) ----
    float dotv[MT];
    #pragma unroll
    for (int t = 0; t < MT; t++) dotv[t] = 0.f;
    {
        const float4* sxr = reinterpret_cast<const float4*>(&s_x[a][0]);
        const float4* f2r = reinterpret_cast<const float4*>(F2g + (long)k * MT * NF);
        #pragma unroll 4
        for (int f = 0; f < NF / 4; f++) {
            float4 xa = sxr[f];
            #pragma unroll
            for (int t = 0; t < MT; t++) {
                float4 b = f2r[t * (NF / 4) + f];
                dotv[t] += xa.x * b.x + xa.y * b.y + xa.z * b.z + xa.w * b.w;
            }
        }
    }
    float Mc[MT];
    #pragma unroll
    for (int t = 0; t < MT; t++)
        Mc[t] = mcoef * (s_f2sq[k * MT + t] - 2.f * dotv[t]);

    // ---- sparse Y1 setup: direct mask or complement (dense rows) ----
    const unsigned mask  = s_mask[a];
    const int      pcnt  = __popc(mask);
    const bool     compl_ = (pcnt > 8);
    const unsigned lmask = compl_ ? (~mask & 0x1FFFFu) : mask;
    const float    sgn   = compl_ ? -1.f : 1.f;

    const float P = 1.0f / 17.0f;
    float lt[MT];
    #pragma unroll
    for (int t = 0; t < MT; t++) lt[t] = 0.f;

    float2* myTrow = reinterpret_cast<float2*>(&s_T[k][a][0]);

    #pragma unroll 1
    for (int it = 0; it < NITER; it++) {
        // softmax over own row (registers only)
        float mx = lt[0];
        #pragma unroll
        for (int t = 1; t < MT; t++) mx = fmaxf(mx, lt[t]);
        float e[MT], ssum = 0.f;
        #pragma unroll
        for (int t = 0; t < MT; t++) { e[t] = __expf(lt[t] - mx); ssum += e[t]; }
        float sc = P / ssum;
        #pragma unroll
        for (int t = 0; t < MT; t++) e[t] *= sc;   // T row

        __syncthreads();   // prior iteration's s_T readers done
        #pragma unroll
        for (int j = 0; j < 5; j++) myTrow[j] = make_float2(e[2 * j], e[2 * j + 1]);
        __syncthreads();

        // cooperative q[k,t] = sum_m T[k,m,t]
        if (a < MT) {
            float s = 0.f;
            #pragma unroll
            for (int m = 0; m < MM; m++) s += s_T[k][m][a];
            s_q[k][a] = s;
        }
        __syncthreads();

        float qv[MT];
        {
            const float2* qr = reinterpret_cast<const float2*>(&s_q[k][0]);
            #pragma unroll
            for (int j = 0; j < 5; j++) {
                float2 v = qr[j];
                qv[2 * j] = v.x; qv[2 * j + 1] = v.y;
            }
        }

        // Y1[a,t] = sum_{b in mask} T[b,t]   (or q - complement sum)
        float y1[MT];
        #pragma unroll
        for (int t = 0; t < MT; t++) y1[t] = compl_ ? qv[t] : 0.f;
        unsigned mm = lmask;
        while (mm) {
            int b = __ffs(mm) - 1;
            mm &= mm - 1;
            const float2* rb = reinterpret_cast<const float2*>(&s_T[k][b][0]);
            #pragma unroll
            for (int j = 0; j < 5; j++) {
                float2 v = rb[j];
                y1[2 * j]     += sgn * v.x;
                y1[2 * j + 1] += sgn * v.y;
            }
        }

        // fused Y2[s] = <Y1, C2[s,:]>, constC2[s] = sum_b q[b]*C2[s,b]^2; update
        #pragma unroll
        for (int s2 = 0; s2 < MT; s2++) {
            const float2* cr = reinterpret_cast<const float2*>(&s_C2[k][s2][0]);
            float y2 = 0.f, cc = 0.f;
            #pragma unroll
            for (int j = 0; j < 5; j++) {
                float2 c = cr[j];
                y2 += y1[2 * j] * c.x + y1[2 * j + 1] * c.y;
                cc += qv[2 * j] * (c.x * c.x) + qv[2 * j + 1] * (c.y * c.y);
            }
            lt[s2] -= gcoef * (cc - 2.f * y2) + Mc[s2];
        }
    }

    // ---- final T and output q ----
    {
        float mx = lt[0];
        #pragma unroll
        for (int t = 1; t < MT; t++) mx = fmaxf(mx, lt[t]);
        float e[MT], ssum = 0.f;
        #pragma unroll
        for (int t = 0; t < MT; t++) { e[t] = __expf(lt[t] - mx); ssum += e[t]; }
        float sc = P / ssum;
        #pragma unroll
        for (int t = 0; t < MT; t++) e[t] *= sc;

        __syncthreads();
        #pragma unroll
        for (int j = 0; j < 5; j++) myTrow[j] = make_float2(e[2 * j], e[2 * j + 1]);
        __syncthreads();

        if (a < MT) {
            float s = 0.f;
            #pragma unroll
            for (int m = 0; m < MM; m++) s += s_T[k][m][a];
            out[(long)n * (NTPL * MT) + k * MT + a] = s;
        }
    }
}

extern "C" void kernel_launch(void* const* d_in, const int* in_sizes, int n_in,
                              void* d_out, int out_size, void* d_ws, size_t ws_size,
                              hipStream_t stream) {
    const float* x      = (const float*)d_in[0];
    const int*   eidx   = (const int*)d_in[1];
    const float* tmpl   = (const float*)d_in[2];
    const float* tmplf  = (const float*)d_in[3];
    const float* alpha0 = (const float*)d_in[4];
    float*       outp   = (float*)d_out;

    const int* dst = eidx + NN * DEG;   // edge_index row 1

    srfgw_kernel<<<dim3(NN), dim3(272), 0, stream>>>(x, dst, tmpl, tmplf, alpha0, outp);
}

// Round 2
// 560.867 us; speedup vs baseline: 1.4171x; 1.4171x over previous
//
#include <hip/hip_runtime.h>

// LTFGW semi-relaxed FGW — round 2: wave-autonomous, C2-in-registers.
// Block = 192 threads (3 waves) handles (node, 8 templates). Each wave owns
// 3 groups of 17 lanes (lanes 51..63 idle); all cross-thread traffic (T, q,
// cc) is intra-wave LDS -> no __syncthreads in the iteration loop (HW keeps
// same-wave DS ops in FIFO order; __builtin_amdgcn_wave_barrier pins compile
// order; fallback if absmax blows up: replace with __threadfence_block()).
// C2 (pre-scaled 2*gcoef*C2) lives in 100 VGPRs -> the 10x10 matvec is pure
// VALU. s_x padded to 132 floats/row (stride 4 mod 32 banks) to kill the
// 17-way Mcost conflicts seen in round 1 (4.6e7 SQ_LDS_BANK_CONFLICT).

#define NN    6000
#define DEG   16
#define MM    17      // M = DEG+1
#define NTPL  16
#define MT    10
#define NF    128
#define NITER 10
#define KPB   8       // templates per block
#define BS    192     // 3 waves
#define XPAD  132     // s_x row stride (33 float4)

__global__ __launch_bounds__(BS) void srfgw_kernel(
    const float* __restrict__ x,        // (6000,128)
    const int*   __restrict__ dst,      // 96000
    const float* __restrict__ C2g,      // (16,10,10)
    const float* __restrict__ F2g,      // (16,10,128)
    const float* __restrict__ alpha0,   // (1,)
    float*       __restrict__ out)      // (6000,160)
{
    const int n   = blockIdx.x;
    const int kb  = blockIdx.y * KPB;
    const int tid = threadIdx.x;

    __shared__ __align__(16) float s_x[MM * XPAD];          // 8976 B
    __shared__ __align__(16) float s_T[KPB][MM][MT];        // 5440 B
    __shared__ __align__(16) float s_C2sq[KPB][MT * MT];    // 3200 B
    __shared__ float s_q[KPB][MT];
    __shared__ float s_cc[KPB][MT];
    __shared__ float s_f2sq[KPB * MT];
    __shared__ int      s_nbr[MM];
    __shared__ unsigned s_mask[MM];

    if (tid < MM) {
        s_nbr[tid]  = (tid == 0) ? n : dst[n * DEG + tid - 1];
        s_mask[tid] = 0u;
    }
    __syncthreads();

    // ---- stage x rows, padded, coalesced float4 ----
    {
        const float4* xg  = reinterpret_cast<const float4*>(x);
        float4*       sx4 = reinterpret_cast<float4*>(s_x);
        for (int i = tid; i < MM * 32; i += BS) {
            int row = i >> 5, col = i & 31;
            sx4[row * 33 + col] = xg[(long)s_nbr[row] * 32 + col];
        }
    }
    // ---- C2^2 into LDS (for cooperative cc) ----
    for (int i = tid; i < KPB * MT * MT; i += BS) {
        float v = C2g[kb * MT * MT + i];
        (&s_C2sq[0][0])[i] = v * v;
    }
    // ---- ||F2||^2 ----
    for (int i = tid; i < KPB * MT; i += BS) {
        const float4* f2 = reinterpret_cast<const float4*>(F2g + (long)(kb * MT + i) * NF);
        float s = 0.f;
        #pragma unroll 8
        for (int f = 0; f < 32; f++) {
            float4 v = f2[f];
            s += v.x * v.x + v.y * v.y + v.z * v.z + v.w * v.w;
        }
        s_f2sq[i] = s;
    }
    // ---- C1 bitmasks ----
    for (int p = tid; p < MM * MM; p += BS) {
        int pa = p / MM, pb = p - pa * MM;
        int u = s_nbr[pa], v = s_nbr[pb];
        const int* du = dst + (long)u * DEG;
        const int* dv = dst + (long)v * DEG;
        bool e = false;
        #pragma unroll
        for (int jj = 0; jj < DEG; jj++) e = e | (du[jj] == v) | (dv[jj] == u);
        if (e) atomicOr(&s_mask[pa], 1u << pb);
    }
    __syncthreads();   // last block-wide barrier

    // ---- lane mapping: 3 groups of 17 per wave ----
    const int  wv    = tid >> 6;
    const int  ln    = tid & 63;
    const int  j3    = ln / 17;            // 0..2 group-in-wave, 3 = idle
    const int  a     = ln - j3 * 17;       // 0..16
    const int  slot  = wv * 3 + j3;        // 0..9 (8,9 unused/idle)
    const bool valid = (j3 < 3) && (slot < KPB);
    const int  ss    = valid ? slot : 0;   // safe LDS index
    const int  k     = kb + ss;

    const float aval   = alpha0[0];
    const float alpha  = 1.f / (1.f + __expf(-aval));
    const float invreg = 10.0f;
    const float gcoef  = 2.f * alpha * invreg;
    const float mcoef  = (1.f - alpha) * invreg;

    // ---- Mc[t] = mcoef*(||F2[k,t]||^2 - 2<x_a, F2[k,t]>)  (before c2s to
    //      keep peak register pressure down) ----
    float Mc[MT];
    {
        float dot[MT];
        #pragma unroll
        for (int t = 0; t < MT; t++) dot[t] = 0.f;
        const float4* sxr = reinterpret_cast<const float4*>(s_x + a * XPAD);
        const float4* f2r = reinterpret_cast<const float4*>(F2g + (long)k * MT * NF);
        for (int f = 0; f < 32; f++) {
            float4 xa = sxr[f];
            #pragma unroll
            for (int t = 0; t < MT; t++) {
                float4 b = f2r[t * 32 + f];
                dot[t] += xa.x * b.x + xa.y * b.y + xa.z * b.z + xa.w * b.w;
            }
        }
        #pragma unroll
        for (int t = 0; t < MT; t++)
            Mc[t] = mcoef * (s_f2sq[ss * MT + t] - 2.f * dot[t]);
    }

    // ---- C2 scaled into registers: c2s[s][t] = 2*gcoef*C2[k,s,t] ----
    float c2s[MT][MT];
    {
        const float tg = 2.f * gcoef;
        const float* c2 = C2g + k * MT * MT;
        #pragma unroll
        for (int s = 0; s < MT; s++)
            #pragma unroll
            for (int t = 0; t < MT; t++)
                c2s[s][t] = tg * c2[s * MT + t];
    }

    // ---- sparse Y1 setup ----
    unsigned mask  = s_mask[a];
    const int  pcnt  = __popc(mask);
    const bool cmpl  = pcnt > 8;
    unsigned   lmask = cmpl ? (~mask & 0x1FFFFu) : mask;
    if (!valid) lmask = 0u;
    const float sgn  = cmpl ? -1.f : 1.f;
    const float P    = 1.f / 17.f;

    float lt[MT];
    #pragma unroll
    for (int t = 0; t < MT; t++) lt[t] = 0.f;

    float2* myTrow = reinterpret_cast<float2*>(&s_T[ss][a][0]);
    float qout = 0.f;

    for (int it = 0; it <= NITER; it++) {
        // thread-local softmax -> T row
        float mx = lt[0];
        #pragma unroll
        for (int t = 1; t < MT; t++) mx = fmaxf(mx, lt[t]);
        float e[MT], ssum = 0.f;
        #pragma unroll
        for (int t = 0; t < MT; t++) { e[t] = __expf(lt[t] - mx); ssum += e[t]; }
        float sc = P / ssum;
        #pragma unroll
        for (int t = 0; t < MT; t++) e[t] *= sc;

        if (valid) {
            #pragma unroll
            for (int q2 = 0; q2 < 5; q2++)
                myTrow[q2] = make_float2(e[2 * q2], e[2 * q2 + 1]);
        }
        __builtin_amdgcn_wave_barrier();

        // cooperative q (conflict-free: bank = 10*j3 + a + 10m mod 32)
        if (valid && a < MT) {
            float s = 0.f;
            #pragma unroll
            for (int m = 0; m < MM; m++) s += s_T[ss][m][a];
            s_q[ss][a] = s;
            qout = s;
        }
        __builtin_amdgcn_wave_barrier();
        if (it == NITER) break;

        float qv[MT];
        {
            const float2* qr = reinterpret_cast<const float2*>(&s_q[ss][0]);
            #pragma unroll
            for (int q2 = 0; q2 < 5; q2++) {
                float2 v = qr[q2];
                qv[2 * q2] = v.x; qv[2 * q2 + 1] = v.y;
            }
        }
        // cooperative cc[s] = gcoef * sum_b q[b]*C2sq[s,b]
        if (valid && a < MT) {
            const float2* cr = reinterpret_cast<const float2*>(&s_C2sq[ss][a * MT]);
            float cc = 0.f;
            #pragma unroll
            for (int q2 = 0; q2 < 5; q2++) {
                float2 c = cr[q2];
                cc += qv[2 * q2] * c.x + qv[2 * q2 + 1] * c.y;
            }
            s_cc[ss][a] = gcoef * cc;
        }
        __builtin_amdgcn_wave_barrier();

        // Y1[a,:] via bitmask (complement trick for dense rows)
        float y1[MT];
        #pragma unroll
        for (int t = 0; t < MT; t++) y1[t] = cmpl ? qv[t] : 0.f;
        unsigned mm = lmask;
        while (mm) {
            int b = __ffs(mm) - 1;
            mm &= mm - 1;
            const float2* rb = reinterpret_cast<const float2*>(&s_T[ss][b][0]);
            #pragma unroll
            for (int q2 = 0; q2 < 5; q2++) {
                float2 v = rb[q2];
                y1[2 * q2]     += sgn * v.x;
                y1[2 * q2 + 1] += sgn * v.y;
            }
        }

        float ccr[MT];
        {
            const float2* cr = reinterpret_cast<const float2*>(&s_cc[ss][0]);
            #pragma unroll
            for (int q2 = 0; q2 < 5; q2++) {
                float2 v = cr[q2];
                ccr[2 * q2] = v.x; ccr[2 * q2 + 1] = v.y;
            }
        }
        // lt[s] += 2*gcoef*y2[s] - gcoef*cc[s] - Mc[s]   (c2s pre-scaled)
        #pragma unroll
        for (int s = 0; s < MT; s++) {
            float y2 = 0.f;
            #pragma unroll
            for (int t = 0; t < MT; t++) y2 += y1[t] * c2s[s][t];
            lt[s] += y2 - ccr[s] - Mc[s];
        }
    }

    if (valid && a < MT)
        out[(long)n * (NTPL * MT) + k * MT + a] = qout;
}

extern "C" void kernel_launch(void* const* d_in, const int* in_sizes, int n_in,
                              void* d_out, int out_size, void* d_ws, size_t ws_size,
                              hipStream_t stream) {
    const float* x      = (const float*)d_in[0];
    const int*   eidx   = (const int*)d_in[1];
    const float* tmpl   = (const float*)d_in[2];
    const float* tmplf  = (const float*)d_in[3];
    const float* alpha0 = (const float*)d_in[4];
    float*       outp   = (float*)d_out;

    const int* dst = eidx + NN * DEG;   // edge_index row 1

    srfgw_kernel<<<dim3(NN, 2), dim3(BS), 0, stream>>>(x, dst, tmpl, tmplf, alpha0, outp);
}

// Round 3
// 311.257 us; speedup vs baseline: 2.5536x; 1.8019x over previous
//
#include <hip/hip_runtime.h>

// LTFGW semi-relaxed FGW — round 3.
// Kernel 1 (gcost): G[v,kt] = mcoef*(||F2[kt]||^2 - 2 x[v].F2[kt]) — hoists the
//   17x-redundant Mcost GEMM out of the main kernel (into d_ws, w/ fallback).
// Kernel 2 (srfgw): block = 512 thr = 8 waves; wave w owns template k=kb+w
//   (wave-uniform -> C2 via readfirstlane/scalar loads, no vmcnt stalls),
//   3 nodes x 17 rows per wave, DPP-row-aligned: rows 0-15 at lanes 16g..16g+15,
//   row 16 at lane 48+g. q = 4x v_add_dpp row_ror (VALU) + row16 via LDS.
//   T rows padded to 48 B -> b128 LDS traffic. No block barriers in the loop.

#define NN    6000
#define DEG   16
#define MM    17
#define NTPL  16
#define MT    10
#define NF    128
#define NITER 10
#define KPB   8
#define NPB   3
#define BS    512
#define RS    12            // padded row stride (floats): 48 B, 16B-aligned

template<int C>
__device__ __forceinline__ float ror_add(float v) {
    int s = __builtin_amdgcn_update_dpp(0, __float_as_int(v), C, 0xf, 0xf, true);
    return v + __int_as_float(s);
}

__global__ __launch_bounds__(256) void gcost_kernel(
    const float* __restrict__ x, const float* __restrict__ F2g,
    const float* __restrict__ alpha0, float* __restrict__ G)
{
    int idx = blockIdx.x * 256 + threadIdx.x;
    if (idx >= NN * NTPL * MT) return;
    int v  = idx / (NTPL * MT);
    int kt = idx - v * (NTPL * MT);
    const float4* xr = reinterpret_cast<const float4*>(x + (size_t)v * NF);
    const float4* fr = reinterpret_cast<const float4*>(F2g + (size_t)kt * NF);
    float d = 0.f, s2 = 0.f;
    #pragma unroll 8
    for (int f = 0; f < NF / 4; f++) {
        float4 a = xr[f], b = fr[f];
        d  += a.x * b.x + a.y * b.y + a.z * b.z + a.w * b.w;
        s2 += b.x * b.x + b.y * b.y + b.z * b.z + b.w * b.w;
    }
    float alpha = 1.f / (1.f + __expf(-alpha0[0]));
    G[idx] = (1.f - alpha) * 10.f * (s2 - 2.f * d);
}

__global__ __launch_bounds__(BS) void srfgw_kernel(
    const float* __restrict__ x,
    const int*   __restrict__ dst,
    const float* __restrict__ C2g,
    const float* __restrict__ F2g,
    const float* __restrict__ alpha0,
    const float* __restrict__ G,
    int useG,
    float*       __restrict__ out)
{
    const int nb  = blockIdx.x * NPB;
    const int kb  = blockIdx.y * KPB;
    const int tid = threadIdx.x;

    __shared__ __align__(16) float s_T[KPB][NPB][MM][RS];     // 19584 B
    __shared__ __align__(16) float s_C2sq[KPB][MT][RS];       // 3840 B (pre-scaled by gcoef)
    __shared__ __align__(16) float s_q[KPB][NPB][RS];
    __shared__ __align__(16) float s_cc[KPB][NPB][RS];
    __shared__ int      s_nbr[NPB][MM];
    __shared__ unsigned s_mask[NPB][MM];

    const float aval  = alpha0[0];
    const float alpha = 1.f / (1.f + __expf(-aval));
    const float gcoef = 2.f * alpha * 10.f;
    const float tg    = 2.f * gcoef;

    if (tid < NPB * MM) {
        int node = tid / MM, a0 = tid - node * MM;
        s_nbr[node][a0]  = (a0 == 0) ? (nb + node) : dst[(size_t)(nb + node) * DEG + a0 - 1];
        s_mask[node][a0] = 0u;
    }
    __syncthreads();

    // ---- C1 bitmasks (3 nodes) ----
    for (int p = tid; p < NPB * MM * MM; p += BS) {
        int node = p / (MM * MM);
        int r    = p - node * MM * MM;
        int pa   = r / MM, pb = r - pa * MM;
        int u = s_nbr[node][pa], v = s_nbr[node][pb];
        const int* du = dst + (size_t)u * DEG;
        const int* dv = dst + (size_t)v * DEG;
        bool e = false;
        #pragma unroll
        for (int j = 0; j < DEG; j++) e = e | (du[j] == v) | (dv[j] == u);
        if (e) atomicOr(&s_mask[node][pa], 1u << pb);
    }
    // ---- C2^2 * gcoef into LDS ----
    for (int i = tid; i < KPB * MT * MT; i += BS) {
        int kk = i / (MT * MT), rr = i - kk * (MT * MT);
        int rs = rr / MT, rt = rr - rs * MT;
        float v = C2g[(size_t)(kb + kk) * MT * MT + rr];
        s_C2sq[kk][rs][rt] = gcoef * v * v;
    }
    __syncthreads();

    // ---- lane mapping: DPP-row-aligned groups ----
    const int  kw    = tid >> 6;
    const int  ln    = tid & 63;
    const bool isR16 = (ln >= 48) && (ln < 51);
    const bool valid = (ln < 51);
    int g = isR16 ? (ln - 48) : (ln >> 4);
    if (g >= NPB) g = 0;                       // lanes 51..63 (invalid)
    const int a = isR16 ? 16 : (ln & 15);

    const int k_u = __builtin_amdgcn_readfirstlane(kb + kw);
    const float* __restrict__ c2p = C2g + (size_t)k_u * MT * MT;

    const int vv = s_nbr[g][a];

    // ---- Mc[t] (precomputed G, or inline fallback) ----
    float Mc[MT];
    if (useG) {
        const float2* gp = reinterpret_cast<const float2*>(G + (size_t)vv * (NTPL * MT) + k_u * MT);
        #pragma unroll
        for (int j = 0; j < 5; j++) {
            float2 w = gp[j];
            Mc[2 * j] = w.x; Mc[2 * j + 1] = w.y;
        }
    } else {
        float dot[MT], sq[MT];
        #pragma unroll
        for (int t = 0; t < MT; t++) { dot[t] = 0.f; sq[t] = 0.f; }
        const float4* xr = reinterpret_cast<const float4*>(x + (size_t)vv * NF);
        const float4* fr = reinterpret_cast<const float4*>(F2g + (size_t)k_u * MT * NF);
        for (int f = 0; f < NF / 4; f++) {
            float4 xa = xr[f];
            #pragma unroll
            for (int t = 0; t < MT; t++) {
                float4 b = fr[t * (NF / 4) + f];
                dot[t] += xa.x * b.x + xa.y * b.y + xa.z * b.z + xa.w * b.w;
                sq[t]  += b.x * b.x + b.y * b.y + b.z * b.z + b.w * b.w;
            }
        }
        const float mcoef = (1.f - alpha) * 10.f;
        #pragma unroll
        for (int t = 0; t < MT; t++) Mc[t] = mcoef * (sq[t] - 2.f * dot[t]);
    }

    // ---- sparse Y1 setup ----
    unsigned mask = valid ? s_mask[g][a] : 0u;
    const int  pcnt = __popc(mask);
    const bool cmpl = pcnt > 8;
    unsigned   lmask = cmpl ? (~mask & 0x1FFFFu) : mask;
    if (!valid) lmask = 0u;
    const float sgn = cmpl ? -1.f : 1.f;
    const float P   = 1.f / 17.f;

    float lt[MT];
    #pragma unroll
    for (int t = 0; t < MT; t++) lt[t] = 0.f;

    float4* Trow = reinterpret_cast<float4*>(&s_T[kw][g][a][0]);
    float q[MT];

    for (int it = 0; it <= NITER; it++) {
        // thread-local softmax -> T row (e kept in regs for DPP q)
        float mx = lt[0];
        #pragma unroll
        for (int t = 1; t < MT; t++) mx = fmaxf(mx, lt[t]);
        float e[MT], ss = 0.f;
        #pragma unroll
        for (int t = 0; t < MT; t++) { e[t] = __expf(lt[t] - mx); ss += e[t]; }
        float sc = P / ss;
        #pragma unroll
        for (int t = 0; t < MT; t++) e[t] *= sc;

        __builtin_amdgcn_wave_barrier();   // prior iter's s_T readers ordered before overwrite
        if (valid) {
            Trow[0] = make_float4(e[0], e[1], e[2], e[3]);
            Trow[1] = make_float4(e[4], e[5], e[6], e[7]);
            reinterpret_cast<float2*>(Trow)[4] = make_float2(e[8], e[9]);
        }
        __builtin_amdgcn_wave_barrier();

        // q via DPP rotate-reduce over the 16-lane row (all lanes get sum)
        #pragma unroll
        for (int t = 0; t < MT; t++) {
            float s = e[t];
            s = ror_add<0x121>(s);
            s = ror_add<0x122>(s);
            s = ror_add<0x124>(s);
            s = ror_add<0x128>(s);
            q[t] = s;
        }
        if (valid && a < 16) {             // add row 16 from LDS
            const float4* r16 = reinterpret_cast<const float4*>(&s_T[kw][g][16][0]);
            float4 ra = r16[0], rb = r16[1];
            float2 rc = reinterpret_cast<const float2*>(r16)[4];
            q[0] += ra.x; q[1] += ra.y; q[2] += ra.z; q[3] += ra.w;
            q[4] += rb.x; q[5] += rb.y; q[6] += rb.z; q[7] += rb.w;
            q[8] += rc.x; q[9] += rc.y;
        }
        if (valid && a == 0) {             // publish q for row-16 lanes + output
            float2* qp = reinterpret_cast<float2*>(&s_q[kw][g][0]);
            #pragma unroll
            for (int j = 0; j < 5; j++) qp[j] = make_float2(q[2 * j], q[2 * j + 1]);
        }
        __builtin_amdgcn_wave_barrier();
        if (isR16) {
            const float2* qp = reinterpret_cast<const float2*>(&s_q[kw][g][0]);
            #pragma unroll
            for (int j = 0; j < 5; j++) {
                float2 w = qp[j];
                q[2 * j] = w.x; q[2 * j + 1] = w.y;
            }
        }
        if (it == NITER) break;

        // cooperative cc[s] = gcoef * sum_b q[b] C2sq[s,b]  (C2sq pre-scaled)
        if (valid && a < MT) {
            const float4* cr = reinterpret_cast<const float4*>(&s_C2sq[kw][a][0]);
            float4 ca = cr[0], cb = cr[1];
            float2 c2 = reinterpret_cast<const float2*>(cr)[4];
            float cc = q[0] * ca.x + q[1] * ca.y + q[2] * ca.z + q[3] * ca.w
                     + q[4] * cb.x + q[5] * cb.y + q[6] * cb.z + q[7] * cb.w
                     + q[8] * c2.x + q[9] * c2.y;
            s_cc[kw][g][a] = cc;
        }
        __builtin_amdgcn_wave_barrier();
        float ccr[MT];
        {
            const float4* cp = reinterpret_cast<const float4*>(&s_cc[kw][g][0]);
            float4 ca = cp[0], cb = cp[1];
            float2 c2 = reinterpret_cast<const float2*>(cp)[4];
            ccr[0] = ca.x; ccr[1] = ca.y; ccr[2] = ca.z; ccr[3] = ca.w;
            ccr[4] = cb.x; ccr[5] = cb.y; ccr[6] = cb.z; ccr[7] = cb.w;
            ccr[8] = c2.x; ccr[9] = c2.y;
        }

        // Y1 via bitmask (complement trick), b128 row reads
        float y1[MT];
        #pragma unroll
        for (int t = 0; t < MT; t++) y1[t] = cmpl ? q[t] : 0.f;
        unsigned mm = lmask;
        while (mm) {
            int b = __ffs(mm) - 1;
            mm &= mm - 1;
            const float4* rb4 = reinterpret_cast<const float4*>(&s_T[kw][g][b][0]);
            float4 ra = rb4[0], rb = rb4[1];
            float2 rc = reinterpret_cast<const float2*>(rb4)[4];
            y1[0] += sgn * ra.x; y1[1] += sgn * ra.y; y1[2] += sgn * ra.z; y1[3] += sgn * ra.w;
            y1[4] += sgn * rb.x; y1[5] += sgn * rb.y; y1[6] += sgn * rb.z; y1[7] += sgn * rb.w;
            y1[8] += sgn * rc.x; y1[9] += sgn * rc.y;
        }

        // y2 matvec with wave-uniform (scalar) C2 + update
        #pragma unroll
        for (int s = 0; s < MT; s++) {
            float y2 = 0.f;
            #pragma unroll
            for (int t = 0; t < MT; t++) y2 = fmaf(y1[t], c2p[s * MT + t], y2);
            lt[s] += tg * y2 - ccr[s] - Mc[s];
        }
    }

    if (valid && a < MT)
        out[(size_t)(nb + g) * (NTPL * MT) + k_u * MT + a] = s_q[kw][g][a];
}

extern "C" void kernel_launch(void* const* d_in, const int* in_sizes, int n_in,
                              void* d_out, int out_size, void* d_ws, size_t ws_size,
                              hipStream_t stream) {
    const float* x      = (const float*)d_in[0];
    const int*   eidx   = (const int*)d_in[1];
    const float* tmpl   = (const float*)d_in[2];
    const float* tmplf  = (const float*)d_in[3];
    const float* alpha0 = (const float*)d_in[4];
    float*       outp   = (float*)d_out;

    const int* dst = eidx + NN * DEG;
    float* G = (float*)d_ws;
    const size_t gbytes = (size_t)NN * NTPL * MT * sizeof(float);
    int useG = (ws_size >= gbytes) ? 1 : 0;

    if (useG)
        gcost_kernel<<<dim3((NN * NTPL * MT + 255) / 256), dim3(256), 0, stream>>>(x, tmplf, alpha0, G);

    srfgw_kernel<<<dim3(NN / NPB, NTPL / KPB), dim3(BS), 0, stream>>>(
        x, dst, tmpl, tmplf, alpha0, G, useG, outp);
}

// Round 5
// 286.667 us; speedup vs baseline: 2.7726x; 1.0858x over previous
//
#include <hip/hip_runtime.h>

// LTFGW semi-relaxed FGW — round 5 (= round 4 + correctness fix).
// ROUND-4 BUG: C2sq staging used `if (tid < KPB*MT*MT)` with KPB=16 ->
//   bound 1600 > BS=1024, so s_C2sq[1024..1599] (templates 10..15) were
//   never initialized -> absmax ~1.0. Fixed with a strided loop. All
//   single-shot `if (tid < N)` staging guards here require N <= BS —
//   adjacency (816) and mask (867) are fine.
// gcost: coalesced via per-chunk transposed-LDS F2.
// srfgw: one block = 3 nodes x ALL 16 templates (16 waves); adjacency in
//   LDS, dual-atomicOr symmetrized masks; exp2-domain logits (log2e folded
//   into tgl / C2sq / G); wave-autonomous loop (DPP q, scalar C2 matvec).

#define NN    6000
#define DEG   16
#define MM    17
#define NTPL  16
#define MT    10
#define NF    128
#define NITER 10
#define KPB   16
#define NPB   3
#define BS    1024
#define RS    12            // padded T row stride (floats)
#define LOG2E 1.44269504088896340736f

template<int C>
__device__ __forceinline__ float ror_add(float v) {
    int s = __builtin_amdgcn_update_dpp(0, __float_as_int(v), C, 0xf, 0xf, true);
    return v + __int_as_float(s);
}

// ---------------- gcost: G[v, k*10+t] = mcoefl*(||F2[kt]||^2 - 2 x[v].F2[kt])
#define GV 8
__global__ __launch_bounds__(320) void gcost_kernel(
    const float* __restrict__ x, const float* __restrict__ F2g,
    const float* __restrict__ alpha0, float* __restrict__ G)
{
    const int tx  = threadIdx.x;          // 0..39 : kt quad
    const int vs  = threadIdx.y;          // 0..7  : node in block
    const int tid = vs * 40 + tx;
    const int v0  = blockIdx.x * GV;

    __shared__ __align__(16) float s_x[GV][NF];        // 4 KB
    __shared__ __align__(16) float s_f2t[16][164];     // 10.5 KB, rows 16B-aligned

    // stage x rows (coalesced float4)
    {
        const float4* xg  = reinterpret_cast<const float4*>(x);
        float4*       sx4 = reinterpret_cast<float4*>(&s_x[0][0]);
        for (int i = tid; i < GV * 32; i += 320) {
            int row = i >> 5, c = i & 31;
            sx4[i] = xg[(size_t)(v0 + row) * 32 + c];
        }
    }

    float4 acc = make_float4(0.f, 0.f, 0.f, 0.f);
    float4 sq  = make_float4(0.f, 0.f, 0.f, 0.f);

    for (int fc = 0; fc < 8; fc++) {
        __syncthreads();
        // stage F2[:, fc*16 .. fc*16+15] transposed: s_f2t[j][kt]
        for (int i = tid; i < 160 * 16; i += 320) {
            int kt = i >> 4, j = i & 15;
            s_f2t[j][kt] = F2g[(size_t)kt * NF + fc * 16 + j];
        }
        __syncthreads();

        const float4* sxr = reinterpret_cast<const float4*>(&s_x[vs][0]);
        #pragma unroll
        for (int u = 0; u < 4; u++) {
            float4 xa = sxr[fc * 4 + u];
            #pragma unroll
            for (int jj = 0; jj < 4; jj++) {
                float xs = (&xa.x)[jj];
                const float4* br = reinterpret_cast<const float4*>(&s_f2t[u * 4 + jj][0]);
                float4 b = br[tx];
                acc.x = fmaf(xs, b.x, acc.x); acc.y = fmaf(xs, b.y, acc.y);
                acc.z = fmaf(xs, b.z, acc.z); acc.w = fmaf(xs, b.w, acc.w);
                sq.x  = fmaf(b.x, b.x, sq.x); sq.y  = fmaf(b.y, b.y, sq.y);
                sq.z  = fmaf(b.z, b.z, sq.z); sq.w  = fmaf(b.w, b.w, sq.w);
            }
        }
    }

    const float alpha  = 1.f / (1.f + __expf(-alpha0[0]));
    const float mcoefl = (1.f - alpha) * 10.f * LOG2E;
    float4 g;
    g.x = mcoefl * (sq.x - 2.f * acc.x);
    g.y = mcoefl * (sq.y - 2.f * acc.y);
    g.z = mcoefl * (sq.z - 2.f * acc.z);
    g.w = mcoefl * (sq.w - 2.f * acc.w);
    float4* Gp = reinterpret_cast<float4*>(G + (size_t)(v0 + vs) * (NTPL * MT));
    Gp[tx] = g;
}

// ---------------- main kernel
__global__ __launch_bounds__(BS) void srfgw_kernel(
    const float* __restrict__ x,
    const int*   __restrict__ dst,
    const float* __restrict__ C2g,
    const float* __restrict__ F2g,
    const float* __restrict__ alpha0,
    const float* __restrict__ G,
    int useG,
    float*       __restrict__ out)
{
    const int nb  = blockIdx.x * NPB;
    const int tid = threadIdx.x;

    __shared__ __align__(16) float s_T[KPB][NPB][MM][RS];     // 39168 B
    __shared__ __align__(16) float s_C2sq[KPB][MT][RS];       // 7680 B (pre-scaled gcoef*log2e)
    __shared__ __align__(16) float s_q[KPB][NPB][RS];         // 2304 B
    __shared__ __align__(16) float s_cc[KPB][NPB][RS];        // 2304 B
    __shared__ __align__(16) int   s_adj[NPB * MM][DEG];      // 3264 B
    __shared__ int      s_nbr[NPB][MM];
    __shared__ unsigned s_mask[NPB][MM];

    const float aval  = alpha0[0];
    const float alpha = 1.f / (1.f + __expf(-aval));
    const float gcoef = 2.f * alpha * 10.f;
    const float tgl   = 2.f * gcoef * LOG2E;       // y2 scale, log2 domain
    const float gl2   = gcoef * LOG2E;             // C2sq prescale

    if (tid < NPB * MM) {
        int node = tid / MM, a0 = tid - node * MM;
        s_nbr[node][a0]  = (a0 == 0) ? (nb + node) : dst[(size_t)(nb + node) * DEG + a0 - 1];
        s_mask[node][a0] = 0u;
    }
    __syncthreads();

    // stage adjacency rows of all 51 neighbors (816 <= BS, single shot ok)
    if (tid < NPB * MM * DEG) {
        int r = tid >> 4, j = tid & 15;
        int node = r / MM, a0 = r - node * MM;
        s_adj[r][j] = dst[(size_t)s_nbr[node][a0] * DEG + j];
    }
    // C2^2 * gcoef*log2e into LDS — STRIDED (1600 > BS; round-4 bug was here)
    for (int i = tid; i < KPB * MT * MT; i += BS) {
        int kk = i / (MT * MT), rr = i - kk * (MT * MT);
        int rs = rr / MT, rt = rr - rs * MT;
        float v = C2g[i];
        s_C2sq[kk][rs][rt] = gl2 * v * v;
    }
    __syncthreads();

    // masks: ordered pair (pa,pb): directed edge nbr[pa]->nbr[pb]?
    // set bit pb of mask[pa] AND bit pa of mask[pb] (symmetrization). 867<=BS.
    if (tid < NPB * MM * MM) {
        int node = tid / (MM * MM), rr = tid - node * (MM * MM);
        int pa = rr / MM, pb = rr - pa * MM;
        int vtgt = s_nbr[node][pb];
        const int* ar = s_adj[node * MM + pa];
        bool e = false;
        #pragma unroll
        for (int j = 0; j < DEG; j++) e = e | (ar[j] == vtgt);
        if (e) {
            atomicOr(&s_mask[node][pa], 1u << pb);
            atomicOr(&s_mask[node][pb], 1u << pa);
        }
    }
    __syncthreads();

    // ---- lane mapping: wave kw owns template kw; 3 groups/wave ----
    const int  kw    = tid >> 6;           // 0..15 == template
    const int  ln    = tid & 63;
    const bool isR16 = (ln >= 48) && (ln < 51);
    const bool valid = (ln < 51);
    int g = isR16 ? (ln - 48) : (ln >> 4);
    if (g >= NPB) g = 0;
    const int a = isR16 ? 16 : (ln & 15);

    const int k_u = __builtin_amdgcn_readfirstlane(kw);
    const float* __restrict__ c2p = C2g + (size_t)k_u * MT * MT;

    const int vv = s_nbr[g][a];

    // ---- Mc (log2-scaled) from G, or inline fallback ----
    float Mc[MT];
    if (useG) {
        const float2* gp = reinterpret_cast<const float2*>(G + (size_t)vv * (NTPL * MT) + k_u * MT);
        #pragma unroll
        for (int j = 0; j < 5; j++) {
            float2 w = gp[j];
            Mc[2 * j] = w.x; Mc[2 * j + 1] = w.y;
        }
    } else {
        float dot[MT], sq2[MT];
        #pragma unroll
        for (int t = 0; t < MT; t++) { dot[t] = 0.f; sq2[t] = 0.f; }
        const float4* xr = reinterpret_cast<const float4*>(x + (size_t)vv * NF);
        const float4* fr = reinterpret_cast<const float4*>(F2g + (size_t)k_u * MT * NF);
        for (int f = 0; f < NF / 4; f++) {
            float4 xa = xr[f];
            #pragma unroll
            for (int t = 0; t < MT; t++) {
                float4 b = fr[t * (NF / 4) + f];
                dot[t] += xa.x * b.x + xa.y * b.y + xa.z * b.z + xa.w * b.w;
                sq2[t] += b.x * b.x + b.y * b.y + b.z * b.z + b.w * b.w;
            }
        }
        const float mcoefl = (1.f - alpha) * 10.f * LOG2E;
        #pragma unroll
        for (int t = 0; t < MT; t++) Mc[t] = mcoefl * (sq2[t] - 2.f * dot[t]);
    }

    // ---- sparse Y1 setup ----
    unsigned mask = valid ? s_mask[g][a] : 0u;
    const int  pcnt = __popc(mask);
    const bool cmpl = pcnt > 8;
    unsigned   lmask = cmpl ? (~mask & 0x1FFFFu) : mask;
    if (!valid) lmask = 0u;
    const float sgn = cmpl ? -1.f : 1.f;
    const float P   = 1.f / 17.f;

    float lt[MT];
    #pragma unroll
    for (int t = 0; t < MT; t++) lt[t] = 0.f;

    float4* Trow = reinterpret_cast<float4*>(&s_T[kw][g][a][0]);
    float q[MT];

    for (int it = 0; it <= NITER; it++) {
        // thread-local softmax (log2 domain: native v_exp)
        float mx = lt[0];
        #pragma unroll
        for (int t = 1; t < MT; t++) mx = fmaxf(mx, lt[t]);
        float e[MT], ss = 0.f;
        #pragma unroll
        for (int t = 0; t < MT; t++) { e[t] = exp2f(lt[t] - mx); ss += e[t]; }
        float sc = P / ss;
        #pragma unroll
        for (int t = 0; t < MT; t++) e[t] *= sc;

        __builtin_amdgcn_wave_barrier();
        if (valid) {
            Trow[0] = make_float4(e[0], e[1], e[2], e[3]);
            Trow[1] = make_float4(e[4], e[5], e[6], e[7]);
            reinterpret_cast<float2*>(Trow)[4] = make_float2(e[8], e[9]);
        }
        __builtin_amdgcn_wave_barrier();

        // q via DPP rotate-reduce over 16-lane row
        #pragma unroll
        for (int t = 0; t < MT; t++) {
            float s = e[t];
            s = ror_add<0x121>(s);
            s = ror_add<0x122>(s);
            s = ror_add<0x124>(s);
            s = ror_add<0x128>(s);
            q[t] = s;
        }
        if (valid && a < 16) {   // add row 16 from LDS
            const float4* r16 = reinterpret_cast<const float4*>(&s_T[kw][g][16][0]);
            float4 ra = r16[0], rb = r16[1];
            float2 rc = reinterpret_cast<const float2*>(r16)[4];
            q[0] += ra.x; q[1] += ra.y; q[2] += ra.z; q[3] += ra.w;
            q[4] += rb.x; q[5] += rb.y; q[6] += rb.z; q[7] += rb.w;
            q[8] += rc.x; q[9] += rc.y;
        }
        if (valid && a == 0) {
            float2* qp = reinterpret_cast<float2*>(&s_q[kw][g][0]);
            #pragma unroll
            for (int j = 0; j < 5; j++) qp[j] = make_float2(q[2 * j], q[2 * j + 1]);
        }
        __builtin_amdgcn_wave_barrier();
        if (isR16) {
            const float2* qp = reinterpret_cast<const float2*>(&s_q[kw][g][0]);
            #pragma unroll
            for (int j = 0; j < 5; j++) {
                float2 w = qp[j];
                q[2 * j] = w.x; q[2 * j + 1] = w.y;
            }
        }
        if (it == NITER) break;

        // cooperative cc[s] (C2sq pre-scaled by gcoef*log2e)
        if (valid && a < MT) {
            const float4* cr = reinterpret_cast<const float4*>(&s_C2sq[kw][a][0]);
            float4 ca = cr[0], cb = cr[1];
            float2 c2 = reinterpret_cast<const float2*>(cr)[4];
            float cc = q[0] * ca.x + q[1] * ca.y + q[2] * ca.z + q[3] * ca.w
                     + q[4] * cb.x + q[5] * cb.y + q[6] * cb.z + q[7] * cb.w
                     + q[8] * c2.x + q[9] * c2.y;
            s_cc[kw][g][a] = cc;
        }
        __builtin_amdgcn_wave_barrier();
        float ccr[MT];
        {
            const float4* cp = reinterpret_cast<const float4*>(&s_cc[kw][g][0]);
            float4 ca = cp[0], cb = cp[1];
            float2 c2 = reinterpret_cast<const float2*>(cp)[4];
            ccr[0] = ca.x; ccr[1] = ca.y; ccr[2] = ca.z; ccr[3] = ca.w;
            ccr[4] = cb.x; ccr[5] = cb.y; ccr[6] = cb.z; ccr[7] = cb.w;
            ccr[8] = c2.x; ccr[9] = c2.y;
        }

        // Y1 via bitmask (complement trick)
        float y1[MT];
        #pragma unroll
        for (int t = 0; t < MT; t++) y1[t] = cmpl ? q[t] : 0.f;
        unsigned mm = lmask;
        while (mm) {
            int b = __ffs(mm) - 1;
            mm &= mm - 1;
            const float4* rb4 = reinterpret_cast<const float4*>(&s_T[kw][g][b][0]);
            float4 ra = rb4[0], rb = rb4[1];
            float2 rc = reinterpret_cast<const float2*>(rb4)[4];
            y1[0] += sgn * ra.x; y1[1] += sgn * ra.y; y1[2] += sgn * ra.z; y1[3] += sgn * ra.w;
            y1[4] += sgn * rb.x; y1[5] += sgn * rb.y; y1[6] += sgn * rb.z; y1[7] += sgn * rb.w;
            y1[8] += sgn * rc.x; y1[9] += sgn * rc.y;
        }

        // y2 matvec (wave-uniform scalar C2) + log2-domain update
        #pragma unroll
        for (int s = 0; s < MT; s++) {
            float y2 = 0.f;
            #pragma unroll
            for (int t = 0; t < MT; t++) y2 = fmaf(y1[t], c2p[s * MT + t], y2);
            lt[s] += tgl * y2 - ccr[s] - Mc[s];
        }
    }

    if (valid && a < MT)
        out[(size_t)(nb + g) * (NTPL * MT) + k_u * MT + a] = s_q[kw][g][a];
}

extern "C" void kernel_launch(void* const* d_in, const int* in_sizes, int n_in,
                              void* d_out, int out_size, void* d_ws, size_t ws_size,
                              hipStream_t stream) {
    const float* x      = (const float*)d_in[0];
    const int*   eidx   = (const int*)d_in[1];
    const float* tmpl   = (const float*)d_in[2];
    const float* tmplf  = (const float*)d_in[3];
    const float* alpha0 = (const float*)d_in[4];
    float*       outp   = (float*)d_out;

    const int* dst = eidx + NN * DEG;
    float* G = (float*)d_ws;
    const size_t gbytes = (size_t)NN * NTPL * MT * sizeof(float);
    int useG = (ws_size >= gbytes) ? 1 : 0;

    if (useG)
        gcost_kernel<<<dim3(NN / GV), dim3(40, 8), 0, stream>>>(x, tmplf, alpha0, G);

    srfgw_kernel<<<dim3(NN / NPB), dim3(BS), 0, stream>>>(
        x, dst, tmpl, tmplf, alpha0, G, useG, outp);
}